// Round 11
// baseline (680.153 us; speedup 1.0000x reference)
//
#include <hip/hip_runtime.h>
#include <hip/hip_bf16.h>

// ---------------- problem constants ----------------
constexpr int N   = 8192;   // nodes
constexpr int F0  = 512;    // nfeat
constexpr int H1  = 128;    // nhid
constexpr int NH  = 2;      // heads
constexpr int C2  = 64;     // nclass
constexpr int CP  = 16;     // cluster_pre
constexpr int NS1 = 8;      // j-slices, layer-1 attention (r9 geometry: 4 blocks/CU)
constexpr int NS2 = 16;     // j-slices, layer-2 attention

typedef __attribute__((ext_vector_type(8))) short  short8;
typedef __attribute__((ext_vector_type(4))) float  float4v;

#define DEVI __device__ __forceinline__

DEVI float bf2f(unsigned short u) { return __uint_as_float(((unsigned int)u) << 16); }
DEVI unsigned short f2bf(float f) {
  unsigned int u = __float_as_uint(f);
  return (unsigned short)((u + 0x7fffu + ((u >> 16) & 1u)) >> 16);   // RNE
}
// packed pair bf16(a) (low 16) | bf16(b) (high 16) via v_cvt_pk_bf16_f32 (RNE)
DEVI unsigned int pk2bf(float a, float b) {
  union { __hip_bfloat162 v; unsigned int u; } c;
  c.v = __float22bfloat162_rn(make_float2(a, b));
  return c.u;
}
DEVI float elu1(float x) { return x > 0.f ? x : __expf(x) - 1.f; }
// exp2(leaky_relu(e2)) where e2 is already scaled by log2(e).
// Positive scaling commutes with max(x, 0.2x), so this equals
// exp(leaky_relu(f1+f2)) when f1,f2 carry the log2e factor. Guard 86.5 = 60*log2e.
DEVI float lrelu_exp2(float e2) {
  e2 = fmaxf(e2, 0.2f * e2);                         // alpha = 0.2
  return exp2f(fminf(e2, 86.5f));
}
DEVI float4v mfma16(short8 a, short8 b, float4v c) {
  return __builtin_amdgcn_mfma_f32_16x16x32_bf16(a, b, c, 0, 0, 0);
}
constexpr float LOG2E = 1.44269504088896340736f;

// ---------------- inline dtype sniff (per wave; no cross-kernel state) --------
DEVI int sniff_wave(const unsigned short* __restrict__ w1) {
  const int lane = threadIdx.x & 63;
  int cnt = 0;
#pragma unroll
  for (int t = 0; t < 16; t++) {
    const float v = bf2f(w1[lane * 16 + t]);
    if (!(fabsf(v) <= 1.0f)) cnt++;                  // catches NaN too
  }
  for (int off = 32; off; off >>= 1) cnt += __shfl_down(cnt, off);
  cnt = __shfl(cnt, 0);
  return (cnt > 64) ? 0 : 1;                         // 1=bf16, 0=f32
}

// ---------------- 0) one fused convert kernel: 6 segments -> bf16 scratch ----
DEVI void cvt_one(const void* __restrict__ src, unsigned short* __restrict__ dst,
                  int idx, int flag) {
  if (flag) {                                    // already bf16: passthrough 4 elems
    ((uint2*)dst)[idx] = ((const uint2*)src)[idx];
  } else {                                       // f32 -> bf16 (RNE, cvt_pk)
    const float4 v = ((const float4*)src)[idx];
    ((uint2*)dst)[idx] = make_uint2(pk2bf(v.x, v.y), pk2bf(v.z, v.w));
  }
}
constexpr int CQ0 = N * F0 / 4;             // x
constexpr int CQ1 = NH * F0 * H1 / 4;       // W_heads
constexpr int CQ2 = NH * 2 * H1 / 4;        // a_heads
constexpr int CQ3 = 2 * H1 * C2 / 4;        // W_out
constexpr int CQ4 = 2 * C2 / 4;             // a_out
constexpr int CQ5 = C2 * CP / 4;            // W1
constexpr int CO1 = CQ0, CO2 = CO1 + CQ1, CO3 = CO2 + CQ2, CO4 = CO3 + CQ3,
              CO5 = CO4 + CQ4, CO6 = CO5 + CQ5;
__global__ __launch_bounds__(256) void k_convert_all(
    const void* s0, const void* s1, const void* s2, const void* s3,
    const void* s4, const void* s5,
    unsigned short* d0, unsigned short* d1, unsigned short* d2,
    unsigned short* d3, unsigned short* d4, unsigned short* d5,
    const unsigned short* __restrict__ w1) {
  const int flag = sniff_wave(w1);
  const int t = blockIdx.x * 256 + threadIdx.x;
  if      (t < CO1) cvt_one(s0, d0, t,       flag);
  else if (t < CO2) cvt_one(s1, d1, t - CO1, flag);
  else if (t < CO3) cvt_one(s2, d2, t - CO2, flag);
  else if (t < CO4) cvt_one(s3, d3, t - CO3, flag);
  else if (t < CO5) cvt_one(s4, d4, t - CO4, flag);
  else if (t < CO6) cvt_one(s5, d5, t - CO5, flag);
}

// ---------------- 1) adj -> bitmask (standalone, 8-VGPR streaming kernel) ----
// (r7 lesson: merging this with the GEMM inherited the GEMM's VGPR count and
// halved the streaming occupancy -> regression. Keep it standalone.)
__global__ __launch_bounds__(256) void k_pack_mask(const int* __restrict__ adj,
                                                   unsigned long long* __restrict__ mb) {
  const size_t t = (size_t)blockIdx.x * 256 + threadIdx.x;     // one int4 = 4 cols
  const int4 a = ((const int4*)adj)[t];
  const unsigned nib = (unsigned)(a.x > 0) | ((unsigned)(a.y > 0) << 1) |
                       ((unsigned)(a.z > 0) << 2) | ((unsigned)(a.w > 0) << 3);
  unsigned long long v = (unsigned long long)nib << ((threadIdx.x & 15) * 4);
  v |= __shfl_xor(v, 1);
  v |= __shfl_xor(v, 2);
  v |= __shfl_xor(v, 4);
  v |= __shfl_xor(v, 8);
  if ((threadIdx.x & 15) == 0) mb[t >> 4] = v;
}

// ---------------- 2) one fused weight-pack kernel (3 segments) ----------------
// W[K][COLS] -> Wp[(k/8)][col][8]
constexpr int PW0 = F0 * H1;                 // head 0
constexpr int PW1 = 2 * F0 * H1;             // + head 1
constexpr int PW2 = PW1 + 2 * H1 * C2;       // + W_out
__global__ __launch_bounds__(256) void k_pack_w_all(const unsigned short* __restrict__ WhdB,
                                                    const unsigned short* __restrict__ WoB,
                                                    unsigned short* __restrict__ WP1,
                                                    unsigned short* __restrict__ WP2) {
  const int t = blockIdx.x * 256 + threadIdx.x;
  if (t < PW1) {
    const int base = (t >= PW0) ? PW0 : 0;
    const int tt = t - base;
    const int k = tt / H1, n = tt % H1;
    WP1[base + ((size_t)(k >> 3) * H1 + n) * 8 + (k & 7)] = WhdB[t];
  } else if (t < PW2) {
    const int tt = t - PW1;
    const int k = tt / C2, n = tt % C2;
    WP2[((size_t)(k >> 3) * C2 + n) * 8 + (k & 7)] = WoB[tt];
  }
}

// ---------------- 3) GEMM C = A @ W (packed) + fused f1/f2 epilogue ----------
// grid.y = head. f1/f2 are written PRE-SCALED by log2(e) (consumed only by
// k_attn's exp2 path).
template <int KDIM, int COLS>
__global__ __launch_bounds__(256) void k_gemm(const unsigned short* __restrict__ A,
                                              const unsigned short* __restrict__ Wp_all,
                                              unsigned short* __restrict__ Cp_all,
                                              const unsigned short* __restrict__ a_all,
                                              float* __restrict__ f1_all,
                                              float* __restrict__ f2_all) {
  constexpr int NT = COLS / 16;
  const int lane = threadIdx.x & 63, w = threadIdx.x >> 6;
  const int quad = lane >> 4, r16 = lane & 15;
  const int head = blockIdx.y;
  const unsigned short* Wp = Wp_all + (size_t)head * KDIM * COLS;
  unsigned short* Cp = Cp_all + (size_t)head * N * COLS;
  const unsigned short* av = a_all + (size_t)head * 2 * COLS;
  float* f1 = f1_all + (size_t)head * N;
  float* f2 = f2_all + (size_t)head * N;
  const int rb = blockIdx.x * 64 + w * 16;
  float4v acc[NT];
#pragma unroll
  for (int nt = 0; nt < NT; nt++) acc[nt] = (float4v){0.f, 0.f, 0.f, 0.f};
  const short* As = (const short*)A;
  const short* Ws = (const short*)Wp;
  for (int kc = 0; kc < KDIM; kc += 32) {
    const short8 af = *(const short8*)(As + (size_t)(rb + r16) * KDIM + kc + quad * 8);
#pragma unroll
    for (int nt = 0; nt < NT; nt++) {
      const short8 bf = *(const short8*)(Ws + ((size_t)((kc >> 3) + quad) * COLS + nt * 16 + r16) * 8);
      acc[nt] = mfma16(af, bf, acc[nt]);
    }
  }
  // a vectors for fused f1/f2
  float a1v[NT], a2v[NT];
#pragma unroll
  for (int nt = 0; nt < NT; nt++) {
    a1v[nt] = bf2f(av[nt * 16 + r16]);
    a2v[nt] = bf2f(av[COLS + nt * 16 + r16]);
  }
  const int row0 = rb + quad * 4;                  // C/D: row=quad*4+reg, col=lane&15
#pragma unroll
  for (int nt = 0; nt < NT; nt++) {
    const int col = nt * 16 + r16;
    const unsigned long long pk =
        (unsigned long long)pk2bf(acc[nt][0], acc[nt][1]) |
        ((unsigned long long)pk2bf(acc[nt][2], acc[nt][3]) << 32);
    *(unsigned long long*)(Cp + ((size_t)(row0 >> 3) * COLS + col) * 8 + (row0 & 7)) = pk;
  }
  // fused f1/f2: per quad-row r, dot over all COLS then reduce across r16 lanes
#pragma unroll
  for (int r = 0; r < 4; r++) {
    float s1 = 0.f, s2 = 0.f;
#pragma unroll
    for (int nt = 0; nt < NT; nt++) { s1 += acc[nt][r] * a1v[nt]; s2 += acc[nt][r] * a2v[nt]; }
    s1 += __shfl_xor(s1, 1); s2 += __shfl_xor(s2, 1);
    s1 += __shfl_xor(s1, 2); s2 += __shfl_xor(s2, 2);
    s1 += __shfl_xor(s1, 4); s2 += __shfl_xor(s2, 4);
    s1 += __shfl_xor(s1, 8); s2 += __shfl_xor(s2, 8);
    if (r16 == 0) { f1[row0 + r] = s1 * LOG2E; f2[row0 + r] = s2 * LOG2E; }
  }
}

// ---------------- 6) attention numerator + fused per-slice denominator -------
// r11 = r9 geometry (128-row blocks, wave owns TWO 16-row m-tiles -> each
// B-fragment load feeds 2 MFMAs; r10's 1-tile variant doubled Wp VMEM and
// regressed) + r10's exp2-on-prescaled-f1/f2 P-build + ILP dsum chains.
template <int COLS>
__global__ __launch_bounds__(256) void k_attn(const unsigned char* __restrict__ mbytes,
                                              const float* __restrict__ f1_all,
                                              const float* __restrict__ f2_all,
                                              const unsigned short* __restrict__ Whp_all,
                                              float* __restrict__ part_all,
                                              float* __restrict__ denp_all, int jspan) {
  constexpr int NT = COLS / 16;
  const int lane = threadIdx.x & 63, w = threadIdx.x >> 6;
  const int quad = lane >> 4, r16 = lane & 15;
  const int head = blockIdx.y;
  const int rb = blockIdx.x * 128 + w * 32;
  const float* f1 = f1_all + (size_t)head * N;
  const float* f2 = f2_all + (size_t)head * N;
  const short* Wp = (const short*)(Whp_all + (size_t)head * N * COLS);
  float* part = part_all + (size_t)(blockIdx.z * gridDim.y + head) * N * COLS;
  float* denp = denp_all + (size_t)(blockIdx.z * gridDim.y + head) * N;
  const float f1r0 = f1[rb + r16];
  const float f1r1 = f1[rb + 16 + r16];
  const unsigned char* mrow0 = mbytes + (size_t)(rb + r16) * (N / 8);
  const unsigned char* mrow1 = mbytes + (size_t)(rb + 16 + r16) * (N / 8);
  float4v acc[2][NT];
#pragma unroll
  for (int mt = 0; mt < 2; mt++)
#pragma unroll
    for (int nt = 0; nt < NT; nt++) acc[mt][nt] = (float4v){0.f, 0.f, 0.f, 0.f};
  float ds0[4] = {0.f, 0.f, 0.f, 0.f};
  float ds1[4] = {0.f, 0.f, 0.f, 0.f};

  const int j0 = blockIdx.z * jspan;
  for (int jcc = j0; jcc < j0 + jspan; jcc += 128) {
    const uint4 M0 = *(const uint4*)(mrow0 + (jcc >> 3));   // 16 aligned bytes = 128 j's
    const uint4 M1 = *(const uint4*)(mrow1 + (jcc >> 3));
    const unsigned mw0[4] = {M0.x, M0.y, M0.z, M0.w};
    const unsigned mw1[4] = {M1.x, M1.y, M1.z, M1.w};
#pragma unroll
    for (int k4 = 0; k4 < 4; k4++) {
      const int jq = jcc + k4 * 32 + quad * 8;
      const float4v fA = *(const float4v*)(f2 + jq);
      const float4v fB = *(const float4v*)(f2 + jq + 4);
      const unsigned m0 = (mw0[k4] >> (quad * 8)) & 0xffu;
      const unsigned m1 = (mw1[k4] >> (quad * 8)) & 0xffu;
      float p0a[8], p1a[8];
#pragma unroll
      for (int jj = 0; jj < 8; jj++) {
        const float fj = (jj < 4) ? fA[jj] : fB[jj - 4];
        float p0 = lrelu_exp2(f1r0 + fj); if (!((m0 >> jj) & 1u)) p0 = 0.f;
        float p1 = lrelu_exp2(f1r1 + fj); if (!((m1 >> jj) & 1u)) p1 = 0.f;
        ds0[jj & 3] += p0; ds1[jj & 3] += p1;      // 4 ILP chains (static idx)
        p0a[jj] = p0; p1a[jj] = p1;
      }
      union { uint4 u; short8 s; } A0, A1;
      A0.u = make_uint4(pk2bf(p0a[0], p0a[1]), pk2bf(p0a[2], p0a[3]),
                        pk2bf(p0a[4], p0a[5]), pk2bf(p0a[6], p0a[7]));
      A1.u = make_uint4(pk2bf(p1a[0], p1a[1]), pk2bf(p1a[2], p1a[3]),
                        pk2bf(p1a[4], p1a[5]), pk2bf(p1a[6], p1a[7]));
#pragma unroll
      for (int nt = 0; nt < NT; nt++) {
        const short8 bf = *(const short8*)(Wp + ((size_t)(jq >> 3) * COLS + nt * 16 + r16) * 8);
        acc[0][nt] = mfma16(A0.s, bf, acc[0][nt]);
        acc[1][nt] = mfma16(A1.s, bf, acc[1][nt]);
      }
    }
  }
  // per-slice denominators: quad-butterfly (each quad covered a disjoint j subset)
  float dsum0 = (ds0[0] + ds0[1]) + (ds0[2] + ds0[3]);
  float dsum1 = (ds1[0] + ds1[1]) + (ds1[2] + ds1[3]);
  dsum0 += __shfl_xor(dsum0, 16); dsum0 += __shfl_xor(dsum0, 32);
  dsum1 += __shfl_xor(dsum1, 16); dsum1 += __shfl_xor(dsum1, 32);
  if (lane < 16) {
    denp[rb + lane] = dsum0;
    denp[rb + 16 + lane] = dsum1;
  }
#pragma unroll
  for (int mt = 0; mt < 2; mt++) {
    const int row0 = rb + mt * 16 + quad * 4;
#pragma unroll
    for (int nt = 0; nt < NT; nt++) {
      const int col = nt * 16 + r16;
#pragma unroll
      for (int r = 0; r < 4; r++) part[(size_t)(row0 + r) * COLS + col] = acc[mt][nt][r];
    }
  }
}

// ---------------- 7) combine slices (numerator + denominator) ----------------
__global__ __launch_bounds__(256) void k_combine1(const float* __restrict__ part,
                                                  const float* __restrict__ denp,
                                                  unsigned short* __restrict__ h) {
  const int t = blockIdx.x * 256 + threadIdx.x;
  const int i = t >> 8, col = t & 255;
  const int head = col >> 7, c = col & 127;
  float s = 0.f, den = 0.f;
#pragma unroll
  for (int sl = 0; sl < NS1; sl++) {
    s   += part[((size_t)(sl * NH + head) * N + i) * H1 + c];
    den += denp[(size_t)(sl * NH + head) * N + i];
  }
  const float v = s / den;
  h[t] = f2bf(elu1(v));
}

// combine2: mu to OUTPUT slot + optional k-packed hi/lo split to d_ws + FUSED
// classpre (a block covers exactly 4 complete mu rows; numerics identical to
// the standalone k_classpre: bf16 world reads back bf2f(f2bf(v))).
__global__ __launch_bounds__(256) void k_combine2(const float* __restrict__ part,
                                                  const float* __restrict__ denp,
                                                  const unsigned short* __restrict__ W1B,
                                                  const unsigned short* __restrict__ w1,
                                                  void* __restrict__ outbase,
                                                  unsigned short* __restrict__ muP,
                                                  unsigned short* __restrict__ muPL) {
  const int flag = sniff_wave(w1);
  __shared__ float mus[4 * C2];
  __shared__ float w1s[C2 * CP];
  const int tid = threadIdx.x;
  const int t = blockIdx.x * 256 + tid;   // N*C2
  const int i = t >> 6;
  float s = 0.f, den = 0.f;
#pragma unroll
  for (int sl = 0; sl < NS2; sl++) {
    s   += part[((size_t)sl * N + i) * C2 + (t & 63)];
    den += denp[(size_t)sl * N + i];
  }
  const float v = elu1(s / den);
  const size_t NN = (size_t)N * N;
  if (flag) ((unsigned short*)outbase)[NN + t] = f2bf(v);
  else      ((float*)outbase)[NN + t] = v;
  if (muP) {
    const int c = t & 63;
    const unsigned short hi = f2bf(v);
    const size_t pa = ((size_t)(c >> 3) * N + i) * 8 + (c & 7);
    muP[pa] = hi;
    muPL[pa] = flag ? (unsigned short)0 : f2bf(v - bf2f(hi));
  }
  // fused classpre
  mus[tid] = flag ? bf2f(f2bf(v)) : v;            // what classpre would read back
#pragma unroll
  for (int q = 0; q < 4; q++) w1s[q * 256 + tid] = bf2f(W1B[q * 256 + tid]);
  __syncthreads();
  if (tid < 4 * CP) {                             // 4 rows x 16 classes = 64 lanes
    const int lr = tid >> 4, c = tid & 15;
    float lg = 0.f;
#pragma unroll
    for (int k = 0; k < C2; k++) lg += mus[lr * C2 + k] * w1s[k * CP + c];
    float mx = lg;
    mx = fmaxf(mx, __shfl_xor(mx, 1));
    mx = fmaxf(mx, __shfl_xor(mx, 2));
    mx = fmaxf(mx, __shfl_xor(mx, 4));
    mx = fmaxf(mx, __shfl_xor(mx, 8));
    const float e = __expf(lg - mx);
    float se = e;
    se += __shfl_xor(se, 1);
    se += __shfl_xor(se, 2);
    se += __shfl_xor(se, 4);
    se += __shfl_xor(se, 8);
    const float o = e / se;
    const int row = blockIdx.x * 4 + lr;
    const size_t off = NN + (size_t)N * C2;
    if (flag) ((unsigned short*)outbase)[off + (size_t)row * CP + c] = f2bf(o);
    else      ((float*)outbase)[off + (size_t)row * CP + c] = o;
  }
}

// ---------------- 9a) recon fast path v7: 32x128 tile, 8 blocks/CU -----------
// Verified r8 version (single-phase write->sync->copy; 16.9KB LDS; thread cap
// reached: 8 blocks x 256 thr = 2048/CU). Grid (N/128, N/32), x=col fastest.
constexpr int RSTR = 132;    // f32 LDS row stride (528B: quad rows 16 banks apart)
__global__ __launch_bounds__(256) void k_recon_fast(const unsigned short* __restrict__ muP,
                                                    const unsigned short* __restrict__ muPL,
                                                    const unsigned short* __restrict__ w1raw,
                                                    void* __restrict__ outbase) {
  const int flag = sniff_wave(w1raw);
  __shared__ float tile[32 * RSTR];                // 16.9 KiB -> 8 blocks/CU
  const int lane = threadIdx.x & 63, w = threadIdx.x >> 6;
  const int quad = lane >> 4, r16 = lane & 15;
  const int rg = w & 1;                            // row-group (16 rows)
  const int ch = w >> 1;                           // col-half (64 cols)
  const int rb0 = blockIdx.y * 32;                 // row-block: SLOW axis
  const int rb = rb0 + rg * 16;
  const int cb = blockIdx.x * 128;                 // col-block: FAST axis
  const short* H = (const short*)muP;
  const short* L = (const short*)muPL;
  float4v acc[4];
#pragma unroll
  for (int nt = 0; nt < 4; nt++) acc[nt] = (float4v){0.f, 0.f, 0.f, 0.f};
#pragma unroll
  for (int kc2 = 0; kc2 < 2; kc2++) {              // kc = kc2*32
    const int kq = kc2 * 4 + quad;                 // k-octet index 0..7
    const short8 ah = *(const short8*)(H + ((size_t)kq * N + rb + r16) * 8);
    short8 al;
    if (!flag) al = *(const short8*)(L + ((size_t)kq * N + rb + r16) * 8);
#pragma unroll
    for (int nt = 0; nt < 4; nt++) {
      const size_t boff = ((size_t)kq * N + cb + ch * 64 + nt * 16 + r16) * 8;
      const short8 bh = *(const short8*)(H + boff);
      acc[nt] = mfma16(ah, bh, acc[nt]);
      if (!flag) {
        const short8 bl = *(const short8*)(L + boff);
        acc[nt] = mfma16(ah, bl, acc[nt]);
        acc[nt] = mfma16(al, bh, acc[nt]);
      }
    }
  }
  // stage to LDS (local row = rg*16 + quad*4 + r, col = ch*64 + nt*16 + r16)
  const int lrow = rg * 16 + quad * 4;
#pragma unroll
  for (int nt = 0; nt < 4; nt++) {
    const int col = ch * 64 + nt * 16 + r16;
#pragma unroll
    for (int r = 0; r < 4; r++) tile[(lrow + r) * RSTR + col] = acc[nt][r];
  }
  __syncthreads();
  // contiguous copy-out (32 rows x 128 cols)
  const int tid = threadIdx.x;
  if (flag) {
    // bf16: 32 rows x 256B; 16 threads/row, 2 iters; cvt_pk during copy
#pragma unroll
    for (int it = 0; it < 2; it++) {
      const int idx = it * 256 + tid;
      const int row = idx >> 4, seg = idx & 15;
      const float4 p = *(const float4*)(tile + row * RSTR + seg * 8);
      const float4 q = *(const float4*)(tile + row * RSTR + seg * 8 + 4);
      const uint4 o = make_uint4(pk2bf(p.x, p.y), pk2bf(p.z, p.w),
                                 pk2bf(q.x, q.y), pk2bf(q.z, q.w));
      *(uint4*)((unsigned short*)outbase + (size_t)(rb0 + row) * N + cb + seg * 8) = o;
    }
  } else {
    // f32: 32 rows x 512B; 32 threads/row, 4 iters
#pragma unroll
    for (int it = 0; it < 4; it++) {
      const int idx = it * 256 + tid;
      const int row = idx >> 5, seg = idx & 31;
      const uint4 o = *(const uint4*)(tile + row * RSTR + seg * 4);
      *(uint4*)((float*)outbase + (size_t)(rb0 + row) * N + cb + seg * 4) = o;
    }
  }
}

// ---------------- 9b) recon fallback (no workspace): round-1 LDS version ----
__global__ __launch_bounds__(256) void k_recon_lds(const unsigned short* __restrict__ w1raw,
                                                   void* __restrict__ outbase) {
  const int flag = sniff_wave(w1raw);
  __shared__ short Ah[8 * 128 * 8];
  __shared__ short Al[8 * 128 * 8];
  __shared__ short Bh[8 * 128 * 8];
  __shared__ short Bl[8 * 128 * 8];
  const int lane = threadIdx.x & 63, w = threadIdx.x >> 6;
  const int quad = lane >> 4, r16 = lane & 15;
  const int rb = blockIdx.x * 128;
  const int cb = blockIdx.y * 128;
  const float* muf = (const float*)((const char*)outbase + (size_t)N * N * 4);
  const short* mub = (const short*)((const char*)outbase + (size_t)N * N * 2);
  const int tq = threadIdx.x >> 5;
  const int tr = threadIdx.x & 31;
#pragma unroll
  for (int it = 0; it < 4; it++) {
    const int r = it * 32 + tr;
#pragma unroll
    for (int side = 0; side < 2; side++) {
      const int grow = (side ? cb : rb) + r;
      short* Hh = side ? Bh : Ah;
      short* Hl = side ? Bl : Al;
      short8 hi, lo;
      if (flag) {
        hi = *(const short8*)(mub + (size_t)grow * C2 + tq * 8);
        lo = (short8){0, 0, 0, 0, 0, 0, 0, 0};
      } else {
        const float4 a = *(const float4*)(muf + (size_t)grow * C2 + tq * 8);
        const float4 b = *(const float4*)(muf + (size_t)grow * C2 + tq * 8 + 4);
        const float vv[8] = {a.x, a.y, a.z, a.w, b.x, b.y, b.z, b.w};
#pragma unroll
        for (int j = 0; j < 8; j++) {
          const unsigned short h = f2bf(vv[j]);
          hi[j] = (short)h;
          lo[j] = (short)f2bf(vv[j] - bf2f(h));
        }
      }
      *(short8*)(Hh + ((size_t)tq * 128 + r) * 8) = hi;
      if (!flag) *(short8*)(Hl + ((size_t)tq * 128 + r) * 8) = lo;
    }
  }
  __syncthreads();
  float4v acc[2][8];
#pragma unroll
  for (int mt = 0; mt < 2; mt++)
#pragma unroll
    for (int nt = 0; nt < 8; nt++) acc[mt][nt] = (float4v){0.f, 0.f, 0.f, 0.f};
#pragma unroll
  for (int kc2 = 0; kc2 < 2; kc2++) {
    const int kq = kc2 * 4 + quad;
    const int ra0 = w * 32 + r16;
    const int ra1 = w * 32 + 16 + r16;
    const short8 ah0 = *(const short8*)(Ah + ((size_t)kq * 128 + ra0) * 8);
    const short8 ah1 = *(const short8*)(Ah + ((size_t)kq * 128 + ra1) * 8);
    if (flag) {
#pragma unroll
      for (int nt = 0; nt < 8; nt++) {
        const short8 bh = *(const short8*)(Bh + ((size_t)kq * 128 + nt * 16 + r16) * 8);
        acc[0][nt] = mfma16(ah0, bh, acc[0][nt]);
        acc[1][nt] = mfma16(ah1, bh, acc[1][nt]);
      }
    } else {
      const short8 al0 = *(const short8*)(Al + ((size_t)kq * 128 + ra0) * 8);
      const short8 al1 = *(const short8*)(Al + ((size_t)kq * 128 + ra1) * 8);
#pragma unroll
      for (int nt = 0; nt < 8; nt++) {
        const short8 bh = *(const short8*)(Bh + ((size_t)kq * 128 + nt * 16 + r16) * 8);
        const short8 bl = *(const short8*)(Bl + ((size_t)kq * 128 + nt * 16 + r16) * 8);
        acc[0][nt] = mfma16(ah0, bh, acc[0][nt]);
        acc[0][nt] = mfma16(ah0, bl, acc[0][nt]);
        acc[0][nt] = mfma16(al0, bh, acc[0][nt]);
        acc[1][nt] = mfma16(ah1, bh, acc[1][nt]);
        acc[1][nt] = mfma16(ah1, bl, acc[1][nt]);
        acc[1][nt] = mfma16(al1, bh, acc[1][nt]);
      }
    }
  }
#pragma unroll
  for (int mt = 0; mt < 2; mt++) {
    const int row0 = rb + w * 32 + mt * 16 + quad * 4;
#pragma unroll
    for (int nt = 0; nt < 8; nt++) {
      const int col = cb + nt * 16 + r16;
#pragma unroll
      for (int r = 0; r < 4; r++) {
        if (flag) ((unsigned short*)outbase)[(size_t)(row0 + r) * N + col] = f2bf(acc[mt][nt][r]);
        else      ((float*)outbase)[(size_t)(row0 + r) * N + col] = acc[mt][nt][r];
      }
    }
  }
}

// fallback classpre (only used when no workspace)
__global__ __launch_bounds__(256) void k_classpre(const unsigned short* __restrict__ W1B,
                                                  const unsigned short* __restrict__ w1raw,
                                                  void* __restrict__ outbase) {
  const int flag = sniff_wave(w1raw);
  __shared__ float w1s[C2 * CP];
  for (int t = threadIdx.x; t < C2 * CP; t += 256) w1s[t] = bf2f(W1B[t]);
  __syncthreads();
  const float* muf = (const float*)((const char*)outbase + (size_t)N * N * 4);
  const unsigned short* mub = (const unsigned short*)((const char*)outbase + (size_t)N * N * 2);
  const int i = blockIdx.x * 256 + threadIdx.x;
  float logit[CP];
#pragma unroll
  for (int c = 0; c < CP; c++) logit[c] = 0.f;
  for (int k = 0; k < C2; k++) {
    const float m = flag ? bf2f(mub[(size_t)i * C2 + k]) : muf[(size_t)i * C2 + k];
#pragma unroll
    for (int c = 0; c < CP; c++) logit[c] += m * w1s[k * CP + c];
  }
  float mx = logit[0];
#pragma unroll
  for (int c = 1; c < CP; c++) mx = fmaxf(mx, logit[c]);
  float se = 0.f;
#pragma unroll
  for (int c = 0; c < CP; c++) { logit[c] = __expf(logit[c] - mx); se += logit[c]; }
  const float inv = 1.f / se;
  const size_t off = (size_t)N * N + (size_t)N * C2;
  if (flag) {
    unsigned short* o = (unsigned short*)outbase + off + (size_t)i * CP;
#pragma unroll
    for (int c = 0; c < CP; c++) o[c] = f2bf(logit[c] * inv);
  } else {
    float* o = (float*)outbase + off + (size_t)i * CP;
#pragma unroll
    for (int c = 0; c < CP; c++) o[c] = logit[c] * inv;
  }
}

// ---------------- launcher ----------------
// All scratch lives in d_out's recon region ([0, 128 MiB), valid for either
// out dtype; r11 total = 128.7 MB < 134.2 MB). Recon launched LAST, reads
// nothing from that region.
extern "C" void kernel_launch(void* const* d_in, const int* in_sizes, int n_in,
                              void* d_out, int out_size, void* d_ws, size_t ws_size,
                              hipStream_t stream) {
  (void)in_sizes; (void)n_in; (void)out_size;
  const void* x   = d_in[0];                       // [N][F0]
  const int*  adj = (const int*)d_in[1];           // [N][N] i32
  const void* Whd = d_in[2];                       // [NH][F0][H1]
  const void* ah  = d_in[3];                       // [NH][2*H1]
  const void* Wo  = d_in[4];                       // [2*H1][C2]
  const void* ao  = d_in[5];                       // [2*C2]
  const unsigned short* W1 = (const unsigned short*)d_in[6];   // [C2][CP]

  char* ob = (char*)d_out;
  size_t off = 0;
  auto take = [&](size_t b) -> char* { char* p = ob + off; off += (b + 255) & ~(size_t)255; return p; };
  unsigned long long* MB = (unsigned long long*)take((size_t)N * N / 8);        //  8 MiB
  float*          PART1 = (float*)take((size_t)NS1 * NH * N * H1 * 4);          // 64 MiB
  float*          PART2 = (float*)take((size_t)NS2 * N * C2 * 4);               // 32 MiB
  unsigned short* Whp   = (unsigned short*)take((size_t)NH * N * H1 * 2);       //  4 MiB
  unsigned short* HBF   = (unsigned short*)take((size_t)N * 2 * H1 * 2);        //  4 MiB
  unsigned short* XB    = (unsigned short*)take((size_t)N * F0 * 2);            //  8 MiB
  unsigned short* Wh2P  = (unsigned short*)take((size_t)N * C2 * 2);            //  1 MiB
  unsigned short* WhdB  = (unsigned short*)take((size_t)NH * F0 * H1 * 2);
  unsigned short* WP1   = (unsigned short*)take((size_t)NH * F0 * H1 * 2);
  unsigned short* WoB   = (unsigned short*)take((size_t)2 * H1 * C2 * 2);
  unsigned short* WP2   = (unsigned short*)take((size_t)2 * H1 * C2 * 2);
  unsigned short* ahB   = (unsigned short*)take((size_t)NH * 2 * H1 * 2);
  unsigned short* aoB   = (unsigned short*)take((size_t)2 * C2 * 2);
  unsigned short* W1B   = (unsigned short*)take((size_t)C2 * CP * 2);
  float*          F1    = (float*)take((size_t)NH * N * 4);
  float*          F2    = (float*)take((size_t)NH * N * 4);
  float*          F1B   = (float*)take((size_t)N * 4);
  float*          F2B   = (float*)take((size_t)N * 4);
  float*          DEN1P = (float*)take((size_t)NS1 * NH * N * 4);               // 512 KiB
  float*          DEN2P = (float*)take((size_t)NS2 * N * 4);                    // 512 KiB
  // total ~128.7 MB < 134.2 MB recon region (either out dtype)

  const bool fast = ws_size >= ((size_t)4 << 20);        // host-side size check only
  unsigned short* muP  = fast ? (unsigned short*)d_ws : nullptr;
  unsigned short* muPL = fast ? (unsigned short*)d_ws + (size_t)N * C2 : nullptr;

  const dim3 B(256);
  k_convert_all<<<dim3((CO6 + 255) / 256), B, 0, stream>>>(x, Whd, ah, Wo, ao, W1,
                                                           XB, WhdB, ahB, WoB, aoB, W1B, W1);
  k_pack_mask<<<dim3((unsigned)((size_t)N * N / 1024)), B, 0, stream>>>(adj, MB);
  k_pack_w_all<<<dim3((PW2 + 255) / 256), B, 0, stream>>>(WhdB, WoB, WP1, WP2);

  k_gemm<F0, H1><<<dim3(N / 64, NH), B, 0, stream>>>(XB, WP1, Whp, ahB, F1, F2);
  k_attn<H1><<<dim3(N / 128, NH, NS1), B, 0, stream>>>((const unsigned char*)MB, F1, F2, Whp,
                                                       PART1, DEN1P, N / NS1);
  k_combine1<<<dim3((N * 2 * H1) / 256), B, 0, stream>>>(PART1, DEN1P, HBF);

  k_gemm<2 * H1, C2><<<dim3(N / 64, 1), B, 0, stream>>>(HBF, WP2, Wh2P, aoB, F1B, F2B);
  k_attn<C2><<<dim3(N / 128, 1, NS2), B, 0, stream>>>((const unsigned char*)MB, F1B, F2B, Wh2P,
                                                      PART2, DEN2P, N / NS2);
  k_combine2<<<dim3((N * C2) / 256), B, 0, stream>>>(PART2, DEN2P, W1B, W1, d_out, muP, muPL);

  if (fast) k_recon_fast<<<dim3(N / 128, N / 32), B, 0, stream>>>(muP, muPL, W1, d_out);
  else {
    k_classpre<<<dim3(N / 256), B, 0, stream>>>(W1B, W1, d_out);   // before recon!
    k_recon_lds<<<dim3(N / 128, N / 128), B, 0, stream>>>(W1, d_out);
  }
}

// Round 12
// 660.056 us; speedup vs baseline: 1.0304x; 1.0304x over previous
//
#include <hip/hip_runtime.h>
#include <hip/hip_bf16.h>

// ---------------- problem constants ----------------
constexpr int N   = 8192;   // nodes
constexpr int F0  = 512;    // nfeat
constexpr int H1  = 128;    // nhid
constexpr int NH  = 2;      // heads
constexpr int C2  = 64;     // nclass
constexpr int CP  = 16;     // cluster_pre
constexpr int NS1 = 8;      // j-slices, layer-1 attention (r9 geometry: 4 blocks/CU)
constexpr int NS2 = 16;     // j-slices, layer-2 attention

typedef __attribute__((ext_vector_type(8))) short  short8;
typedef __attribute__((ext_vector_type(4))) float  float4v;

#define DEVI __device__ __forceinline__

DEVI float bf2f(unsigned short u) { return __uint_as_float(((unsigned int)u) << 16); }
DEVI unsigned short f2bf(float f) {
  unsigned int u = __float_as_uint(f);
  return (unsigned short)((u + 0x7fffu + ((u >> 16) & 1u)) >> 16);   // RNE
}
// packed pair bf16(a) (low 16) | bf16(b) (high 16) via v_cvt_pk_bf16_f32 (RNE)
DEVI unsigned int pk2bf(float a, float b) {
  union { __hip_bfloat162 v; unsigned int u; } c;
  c.v = __float22bfloat162_rn(make_float2(a, b));
  return c.u;
}
DEVI float elu1(float x) { return x > 0.f ? x : __expf(x) - 1.f; }
DEVI float lrelu_exp(float e) {                      // exp(leaky_relu(e)), overflow-guarded
  e = fmaxf(e, 0.2f * e);                            // alpha = 0.2
  return __expf(fminf(e, 60.f));
}
DEVI float4v mfma16(short8 a, short8 b, float4v c) {
  return __builtin_amdgcn_mfma_f32_16x16x32_bf16(a, b, c, 0, 0, 0);
}

// ---------------- inline dtype sniff (per wave; no cross-kernel state) --------
DEVI int sniff_wave(const unsigned short* __restrict__ w1) {
  const int lane = threadIdx.x & 63;
  int cnt = 0;
#pragma unroll
  for (int t = 0; t < 16; t++) {
    const float v = bf2f(w1[lane * 16 + t]);
    if (!(fabsf(v) <= 1.0f)) cnt++;                  // catches NaN too
  }
  for (int off = 32; off; off >>= 1) cnt += __shfl_down(cnt, off);
  cnt = __shfl(cnt, 0);
  return (cnt > 64) ? 0 : 1;                         // 1=bf16, 0=f32
}

// ---------------- helpers for fused setup kernel ----------------
DEVI void cvt_one(const void* __restrict__ src, unsigned short* __restrict__ dst,
                  int idx, int flag) {
  if (flag) {                                    // already bf16: passthrough 4 elems
    ((uint2*)dst)[idx] = ((const uint2*)src)[idx];
  } else {                                       // f32 -> bf16 (RNE, cvt_pk)
    const float4 v = ((const float4*)src)[idx];
    ((uint2*)dst)[idx] = make_uint2(pk2bf(v.x, v.y), pk2bf(v.z, v.w));
  }
}
DEVI unsigned short cvt_elem(const void* __restrict__ src, int idx, int flag) {
  return flag ? ((const unsigned short*)src)[idx]
              : f2bf(((const float*)src)[idx]);
}

// segment sizes (in 4-elem quads) for the convert branch: x, a_heads, a_out, W1
constexpr int CQ0 = N * F0 / 4;             // x
constexpr int CQ2 = NH * 2 * H1 / 4;        // a_heads
constexpr int CQ4 = 2 * C2 / 4;             // a_out
constexpr int CQ5 = C2 * CP / 4;            // W1
constexpr int CVQ = CQ0 + CQ2 + CQ4 + CQ5;
// weight-pack sizes (elements)
constexpr int PW0 = F0 * H1;                // head 0
constexpr int PW1 = 2 * F0 * H1;            // + head 1
constexpr int PW2 = PW1 + 2 * H1 * C2;      // + W_out
// block partition of the fused setup grid
constexpr int MBB = (int)((size_t)N * N / 1024);     // 65536 mask blocks (int4/thread)
constexpr int CVB = (CVQ + 255) / 256;               // convert blocks
constexpr int PKB = (PW2 + 255) / 256;               // weight-pack blocks

// ---------------- 0) fused setup: mask pack + converts + weight pack ---------
// All three phases are independent streaming work (<=~24 VGPR per branch --
// r7's VGPR-inheritance failure mode doesn't apply; no GEMM branch here).
// Mask blocks (256MB adj read, the dominant stream) dispatch first; convert
// (8.5MB) and weight-pack (0.3MB, converts DIRECTLY from raw -> packed,
// bit-identical to the old convert-then-pack) backfill under it.
__global__ __launch_bounds__(256) void k_setup(
    const int* __restrict__ adj, unsigned long long* __restrict__ mb,
    const void* __restrict__ x, const void* __restrict__ ah,
    const void* __restrict__ ao, const unsigned short* __restrict__ w1raw,
    unsigned short* __restrict__ XB, unsigned short* __restrict__ ahB,
    unsigned short* __restrict__ aoB, unsigned short* __restrict__ W1B,
    const void* __restrict__ Whd, const void* __restrict__ Wo,
    unsigned short* __restrict__ WP1, unsigned short* __restrict__ WP2) {
  const unsigned bid = blockIdx.x;
  if (bid < (unsigned)MBB) {
    // ---- adj -> bitmask (int4 per thread, u64 shfl-OR pack) ----
    const size_t t = (size_t)bid * 256 + threadIdx.x;
    const int4 a = ((const int4*)adj)[t];
    const unsigned nib = (unsigned)(a.x > 0) | ((unsigned)(a.y > 0) << 1) |
                         ((unsigned)(a.z > 0) << 2) | ((unsigned)(a.w > 0) << 3);
    unsigned long long v = (unsigned long long)nib << ((threadIdx.x & 15) * 4);
    v |= __shfl_xor(v, 1);
    v |= __shfl_xor(v, 2);
    v |= __shfl_xor(v, 4);
    v |= __shfl_xor(v, 8);
    if ((threadIdx.x & 15) == 0) mb[t >> 4] = v;
  } else if (bid < (unsigned)(MBB + CVB)) {
    // ---- convert x / a_heads / a_out / W1 -> bf16 scratch ----
    const int flag = sniff_wave(w1raw);
    const int q = (int)(bid - MBB) * 256 + (int)threadIdx.x;
    if      (q < CQ0)                   cvt_one(x,     XB,  q, flag);
    else if (q < CQ0 + CQ2)             cvt_one(ah,    ahB, q - CQ0, flag);
    else if (q < CQ0 + CQ2 + CQ4)       cvt_one(ao,    aoB, q - CQ0 - CQ2, flag);
    else if (q < CVQ)                   cvt_one(w1raw, W1B, q - CQ0 - CQ2 - CQ4, flag);
  } else {
    // ---- weight pack W[K][COLS] -> Wp[(k/8)][col][8], direct from raw ----
    const int flag = sniff_wave(w1raw);
    const int t = (int)(bid - MBB - CVB) * 256 + (int)threadIdx.x;
    if (t < PW1) {
      const int base = (t >= PW0) ? PW0 : 0;
      const int tt = t - base;
      const int k = tt / H1, n = tt % H1;
      WP1[base + ((size_t)(k >> 3) * H1 + n) * 8 + (k & 7)] = cvt_elem(Whd, t, flag);
    } else if (t < PW2) {
      const int tt = t - PW1;
      const int k = tt / C2, n = tt % C2;
      WP2[((size_t)(k >> 3) * C2 + n) * 8 + (k & 7)] = cvt_elem(Wo, tt, flag);
    }
  }
}

// ---------------- 3) GEMM C = A @ W (packed) + fused f1/f2 epilogue ----------
// grid.y = head. Outputs only packed bf16 C (Cp) and f32 f1/f2 (no f32 C).
template <int KDIM, int COLS>
__global__ __launch_bounds__(256) void k_gemm(const unsigned short* __restrict__ A,
                                              const unsigned short* __restrict__ Wp_all,
                                              unsigned short* __restrict__ Cp_all,
                                              const unsigned short* __restrict__ a_all,
                                              float* __restrict__ f1_all,
                                              float* __restrict__ f2_all) {
  constexpr int NT = COLS / 16;
  const int lane = threadIdx.x & 63, w = threadIdx.x >> 6;
  const int quad = lane >> 4, r16 = lane & 15;
  const int head = blockIdx.y;
  const unsigned short* Wp = Wp_all + (size_t)head * KDIM * COLS;
  unsigned short* Cp = Cp_all + (size_t)head * N * COLS;
  const unsigned short* av = a_all + (size_t)head * 2 * COLS;
  float* f1 = f1_all + (size_t)head * N;
  float* f2 = f2_all + (size_t)head * N;
  const int rb = blockIdx.x * 64 + w * 16;
  float4v acc[NT];
#pragma unroll
  for (int nt = 0; nt < NT; nt++) acc[nt] = (float4v){0.f, 0.f, 0.f, 0.f};
  const short* As = (const short*)A;
  const short* Ws = (const short*)Wp;
  for (int kc = 0; kc < KDIM; kc += 32) {
    const short8 af = *(const short8*)(As + (size_t)(rb + r16) * KDIM + kc + quad * 8);
#pragma unroll
    for (int nt = 0; nt < NT; nt++) {
      const short8 bf = *(const short8*)(Ws + ((size_t)((kc >> 3) + quad) * COLS + nt * 16 + r16) * 8);
      acc[nt] = mfma16(af, bf, acc[nt]);
    }
  }
  // a vectors for fused f1/f2
  float a1v[NT], a2v[NT];
#pragma unroll
  for (int nt = 0; nt < NT; nt++) {
    a1v[nt] = bf2f(av[nt * 16 + r16]);
    a2v[nt] = bf2f(av[COLS + nt * 16 + r16]);
  }
  const int row0 = rb + quad * 4;                  // C/D: row=quad*4+reg, col=lane&15
#pragma unroll
  for (int nt = 0; nt < NT; nt++) {
    const int col = nt * 16 + r16;
    const unsigned long long pk =
        (unsigned long long)pk2bf(acc[nt][0], acc[nt][1]) |
        ((unsigned long long)pk2bf(acc[nt][2], acc[nt][3]) << 32);
    *(unsigned long long*)(Cp + ((size_t)(row0 >> 3) * COLS + col) * 8 + (row0 & 7)) = pk;
  }
  // fused f1/f2: per quad-row r, dot over all COLS then reduce across r16 lanes
#pragma unroll
  for (int r = 0; r < 4; r++) {
    float s1 = 0.f, s2 = 0.f;
#pragma unroll
    for (int nt = 0; nt < NT; nt++) { s1 += acc[nt][r] * a1v[nt]; s2 += acc[nt][r] * a2v[nt]; }
    s1 += __shfl_xor(s1, 1); s2 += __shfl_xor(s2, 1);
    s1 += __shfl_xor(s1, 2); s2 += __shfl_xor(s2, 2);
    s1 += __shfl_xor(s1, 4); s2 += __shfl_xor(s2, 4);
    s1 += __shfl_xor(s1, 8); s2 += __shfl_xor(s2, 8);
    if (r16 == 0) { f1[row0 + r] = s1; f2[row0 + r] = s2; }
  }
}

// ---------------- 6) attention numerator + fused per-slice denominator -------
// r9-verified geometry: 128-row blocks, wave owns TWO 16-row m-tiles (each
// B-fragment load feeds 2 MFMAs); dsum in 4 ILP chains.
template <int COLS>
__global__ __launch_bounds__(256) void k_attn(const unsigned char* __restrict__ mbytes,
                                              const float* __restrict__ f1_all,
                                              const float* __restrict__ f2_all,
                                              const unsigned short* __restrict__ Whp_all,
                                              float* __restrict__ part_all,
                                              float* __restrict__ denp_all, int jspan) {
  constexpr int NT = COLS / 16;
  const int lane = threadIdx.x & 63, w = threadIdx.x >> 6;
  const int quad = lane >> 4, r16 = lane & 15;
  const int head = blockIdx.y;
  const int rb = blockIdx.x * 128 + w * 32;
  const float* f1 = f1_all + (size_t)head * N;
  const float* f2 = f2_all + (size_t)head * N;
  const short* Wp = (const short*)(Whp_all + (size_t)head * N * COLS);
  float* part = part_all + (size_t)(blockIdx.z * gridDim.y + head) * N * COLS;
  float* denp = denp_all + (size_t)(blockIdx.z * gridDim.y + head) * N;
  const float f1r0 = f1[rb + r16];
  const float f1r1 = f1[rb + 16 + r16];
  const unsigned char* mrow0 = mbytes + (size_t)(rb + r16) * (N / 8);
  const unsigned char* mrow1 = mbytes + (size_t)(rb + 16 + r16) * (N / 8);
  float4v acc[2][NT];
#pragma unroll
  for (int mt = 0; mt < 2; mt++)
#pragma unroll
    for (int nt = 0; nt < NT; nt++) acc[mt][nt] = (float4v){0.f, 0.f, 0.f, 0.f};
  float ds0[4] = {0.f, 0.f, 0.f, 0.f};
  float ds1[4] = {0.f, 0.f, 0.f, 0.f};

  const int j0 = blockIdx.z * jspan;
  for (int jcc = j0; jcc < j0 + jspan; jcc += 128) {
    const uint4 M0 = *(const uint4*)(mrow0 + (jcc >> 3));   // 16 aligned bytes = 128 j's
    const uint4 M1 = *(const uint4*)(mrow1 + (jcc >> 3));
    const unsigned mw0[4] = {M0.x, M0.y, M0.z, M0.w};
    const unsigned mw1[4] = {M1.x, M1.y, M1.z, M1.w};
#pragma unroll
    for (int k4 = 0; k4 < 4; k4++) {
      const int jq = jcc + k4 * 32 + quad * 8;
      const float4v fA = *(const float4v*)(f2 + jq);
      const float4v fB = *(const float4v*)(f2 + jq + 4);
      const unsigned m0 = (mw0[k4] >> (quad * 8)) & 0xffu;
      const unsigned m1 = (mw1[k4] >> (quad * 8)) & 0xffu;
      float p0a[8], p1a[8];
#pragma unroll
      for (int jj = 0; jj < 8; jj++) {
        const float fj = (jj < 4) ? fA[jj] : fB[jj - 4];
        float p0 = lrelu_exp(f1r0 + fj); if (!((m0 >> jj) & 1u)) p0 = 0.f;
        float p1 = lrelu_exp(f1r1 + fj); if (!((m1 >> jj) & 1u)) p1 = 0.f;
        ds0[jj & 3] += p0; ds1[jj & 3] += p1;      // 4 ILP chains (static idx)
        p0a[jj] = p0; p1a[jj] = p1;
      }
      union { uint4 u; short8 s; } A0, A1;
      A0.u = make_uint4(pk2bf(p0a[0], p0a[1]), pk2bf(p0a[2], p0a[3]),
                        pk2bf(p0a[4], p0a[5]), pk2bf(p0a[6], p0a[7]));
      A1.u = make_uint4(pk2bf(p1a[0], p1a[1]), pk2bf(p1a[2], p1a[3]),
                        pk2bf(p1a[4], p1a[5]), pk2bf(p1a[6], p1a[7]));
#pragma unroll
      for (int nt = 0; nt < NT; nt++) {
        const short8 bf = *(const short8*)(Wp + ((size_t)(jq >> 3) * COLS + nt * 16 + r16) * 8);
        acc[0][nt] = mfma16(A0.s, bf, acc[0][nt]);
        acc[1][nt] = mfma16(A1.s, bf, acc[1][nt]);
      }
    }
  }
  // per-slice denominators: quad-butterfly (each quad covered a disjoint j subset)
  float dsum0 = (ds0[0] + ds0[1]) + (ds0[2] + ds0[3]);
  float dsum1 = (ds1[0] + ds1[1]) + (ds1[2] + ds1[3]);
  dsum0 += __shfl_xor(dsum0, 16); dsum0 += __shfl_xor(dsum0, 32);
  dsum1 += __shfl_xor(dsum1, 16); dsum1 += __shfl_xor(dsum1, 32);
  if (lane < 16) {
    denp[rb + lane] = dsum0;
    denp[rb + 16 + lane] = dsum1;
  }
#pragma unroll
  for (int mt = 0; mt < 2; mt++) {
    const int row0 = rb + mt * 16 + quad * 4;
#pragma unroll
    for (int nt = 0; nt < NT; nt++) {
      const int col = nt * 16 + r16;
#pragma unroll
      for (int r = 0; r < 4; r++) part[(size_t)(row0 + r) * COLS + col] = acc[mt][nt][r];
    }
  }
}

// ---------------- 7) combine slices (numerator + denominator) ----------------
__global__ __launch_bounds__(256) void k_combine1(const float* __restrict__ part,
                                                  const float* __restrict__ denp,
                                                  unsigned short* __restrict__ h) {
  const int t = blockIdx.x * 256 + threadIdx.x;
  const int i = t >> 8, col = t & 255;
  const int head = col >> 7, c = col & 127;
  float s = 0.f, den = 0.f;
#pragma unroll
  for (int sl = 0; sl < NS1; sl++) {
    s   += part[((size_t)(sl * NH + head) * N + i) * H1 + c];
    den += denp[(size_t)(sl * NH + head) * N + i];
  }
  const float v = s / den;
  h[t] = f2bf(elu1(v));
}

// combine2: mu to OUTPUT slot + optional k-packed hi/lo split to d_ws + FUSED
// classpre (a block covers exactly 4 complete mu rows; numerics identical to
// the standalone k_classpre: bf16 world reads back bf2f(f2bf(v))).
__global__ __launch_bounds__(256) void k_combine2(const float* __restrict__ part,
                                                  const float* __restrict__ denp,
                                                  const unsigned short* __restrict__ W1B,
                                                  const unsigned short* __restrict__ w1,
                                                  void* __restrict__ outbase,
                                                  unsigned short* __restrict__ muP,
                                                  unsigned short* __restrict__ muPL) {
  const int flag = sniff_wave(w1);
  __shared__ float mus[4 * C2];
  __shared__ float w1s[C2 * CP];
  const int tid = threadIdx.x;
  const int t = blockIdx.x * 256 + tid;   // N*C2
  const int i = t >> 6;
  float s = 0.f, den = 0.f;
#pragma unroll
  for (int sl = 0; sl < NS2; sl++) {
    s   += part[((size_t)sl * N + i) * C2 + (t & 63)];
    den += denp[(size_t)sl * N + i];
  }
  const float v = elu1(s / den);
  const size_t NN = (size_t)N * N;
  if (flag) ((unsigned short*)outbase)[NN + t] = f2bf(v);
  else      ((float*)outbase)[NN + t] = v;
  if (muP) {
    const int c = t & 63;
    const unsigned short hi = f2bf(v);
    const size_t pa = ((size_t)(c >> 3) * N + i) * 8 + (c & 7);
    muP[pa] = hi;
    muPL[pa] = flag ? (unsigned short)0 : f2bf(v - bf2f(hi));
  }
  // fused classpre
  mus[tid] = flag ? bf2f(f2bf(v)) : v;            // what classpre would read back
#pragma unroll
  for (int q = 0; q < 4; q++) w1s[q * 256 + tid] = bf2f(W1B[q * 256 + tid]);
  __syncthreads();
  if (tid < 4 * CP) {                             // 4 rows x 16 classes = 64 lanes
    const int lr = tid >> 4, c = tid & 15;
    float lg = 0.f;
#pragma unroll
    for (int k = 0; k < C2; k++) lg += mus[lr * C2 + k] * w1s[k * CP + c];
    float mx = lg;
    mx = fmaxf(mx, __shfl_xor(mx, 1));
    mx = fmaxf(mx, __shfl_xor(mx, 2));
    mx = fmaxf(mx, __shfl_xor(mx, 4));
    mx = fmaxf(mx, __shfl_xor(mx, 8));
    const float e = __expf(lg - mx);
    float se = e;
    se += __shfl_xor(se, 1);
    se += __shfl_xor(se, 2);
    se += __shfl_xor(se, 4);
    se += __shfl_xor(se, 8);
    const float o = e / se;
    const int row = blockIdx.x * 4 + lr;
    const size_t off = NN + (size_t)N * C2;
    if (flag) ((unsigned short*)outbase)[off + (size_t)row * CP + c] = f2bf(o);
    else      ((float*)outbase)[off + (size_t)row * CP + c] = o;
  }
}

// ---------------- 9a) recon fast path: 32x128 tile, 8 blocks/CU --------------
// Verified r8 version (single-phase write->sync->copy; 16.9KB LDS; thread cap
// reached: 8 blocks x 256 thr = 2048/CU). Grid (N/128, N/32), x=col fastest.
constexpr int RSTR = 132;    // f32 LDS row stride (528B: quad rows 16 banks apart)
__global__ __launch_bounds__(256) void k_recon_fast(const unsigned short* __restrict__ muP,
                                                    const unsigned short* __restrict__ muPL,
                                                    const unsigned short* __restrict__ w1raw,
                                                    void* __restrict__ outbase) {
  const int flag = sniff_wave(w1raw);
  __shared__ float tile[32 * RSTR];                // 16.9 KiB -> 8 blocks/CU
  const int lane = threadIdx.x & 63, w = threadIdx.x >> 6;
  const int quad = lane >> 4, r16 = lane & 15;
  const int rg = w & 1;                            // row-group (16 rows)
  const int ch = w >> 1;                           // col-half (64 cols)
  const int rb0 = blockIdx.y * 32;                 // row-block: SLOW axis
  const int rb = rb0 + rg * 16;
  const int cb = blockIdx.x * 128;                 // col-block: FAST axis
  const short* H = (const short*)muP;
  const short* L = (const short*)muPL;
  float4v acc[4];
#pragma unroll
  for (int nt = 0; nt < 4; nt++) acc[nt] = (float4v){0.f, 0.f, 0.f, 0.f};
#pragma unroll
  for (int kc2 = 0; kc2 < 2; kc2++) {              // kc = kc2*32
    const int kq = kc2 * 4 + quad;                 // k-octet index 0..7
    const short8 ah = *(const short8*)(H + ((size_t)kq * N + rb + r16) * 8);
    short8 al;
    if (!flag) al = *(const short8*)(L + ((size_t)kq * N + rb + r16) * 8);
#pragma unroll
    for (int nt = 0; nt < 4; nt++) {
      const size_t boff = ((size_t)kq * N + cb + ch * 64 + nt * 16 + r16) * 8;
      const short8 bh = *(const short8*)(H + boff);
      acc[nt] = mfma16(ah, bh, acc[nt]);
      if (!flag) {
        const short8 bl = *(const short8*)(L + boff);
        acc[nt] = mfma16(ah, bl, acc[nt]);
        acc[nt] = mfma16(al, bh, acc[nt]);
      }
    }
  }
  // stage to LDS (local row = rg*16 + quad*4 + r, col = ch*64 + nt*16 + r16)
  const int lrow = rg * 16 + quad * 4;
#pragma unroll
  for (int nt = 0; nt < 4; nt++) {
    const int col = ch * 64 + nt * 16 + r16;
#pragma unroll
    for (int r = 0; r < 4; r++) tile[(lrow + r) * RSTR + col] = acc[nt][r];
  }
  __syncthreads();
  // contiguous copy-out (32 rows x 128 cols)
  const int tid = threadIdx.x;
  if (flag) {
    // bf16: 32 rows x 256B; 16 threads/row, 2 iters; cvt_pk during copy
#pragma unroll
    for (int it = 0; it < 2; it++) {
      const int idx = it * 256 + tid;
      const int row = idx >> 4, seg = idx & 15;
      const float4 p = *(const float4*)(tile + row * RSTR + seg * 8);
      const float4 q = *(const float4*)(tile + row * RSTR + seg * 8 + 4);
      const uint4 o = make_uint4(pk2bf(p.x, p.y), pk2bf(p.z, p.w),
                                 pk2bf(q.x, q.y), pk2bf(q.z, q.w));
      *(uint4*)((unsigned short*)outbase + (size_t)(rb0 + row) * N + cb + seg * 8) = o;
    }
  } else {
    // f32: 32 rows x 512B; 32 threads/row, 4 iters
#pragma unroll
    for (int it = 0; it < 4; it++) {
      const int idx = it * 256 + tid;
      const int row = idx >> 5, seg = idx & 31;
      const uint4 o = *(const uint4*)(tile + row * RSTR + seg * 4);
      *(uint4*)((float*)outbase + (size_t)(rb0 + row) * N + cb + seg * 4) = o;
    }
  }
}

// ---------------- 9b) recon fallback (no workspace): round-1 LDS version ----
__global__ __launch_bounds__(256) void k_recon_lds(const unsigned short* __restrict__ w1raw,
                                                   void* __restrict__ outbase) {
  const int flag = sniff_wave(w1raw);
  __shared__ short Ah[8 * 128 * 8];
  __shared__ short Al[8 * 128 * 8];
  __shared__ short Bh[8 * 128 * 8];
  __shared__ short Bl[8 * 128 * 8];
  const int lane = threadIdx.x & 63, w = threadIdx.x >> 6;
  const int quad = lane >> 4, r16 = lane & 15;
  const int rb = blockIdx.x * 128;
  const int cb = blockIdx.y * 128;
  const float* muf = (const float*)((const char*)outbase + (size_t)N * N * 4);
  const short* mub = (const short*)((const char*)outbase + (size_t)N * N * 2);
  const int tq = threadIdx.x >> 5;
  const int tr = threadIdx.x & 31;
#pragma unroll
  for (int it = 0; it < 4; it++) {
    const int r = it * 32 + tr;
#pragma unroll
    for (int side = 0; side < 2; side++) {
      const int grow = (side ? cb : rb) + r;
      short* Hh = side ? Bh : Ah;
      short* Hl = side ? Bl : Al;
      short8 hi, lo;
      if (flag) {
        hi = *(const short8*)(mub + (size_t)grow * C2 + tq * 8);
        lo = (short8){0, 0, 0, 0, 0, 0, 0, 0};
      } else {
        const float4 a = *(const float4*)(muf + (size_t)grow * C2 + tq * 8);
        const float4 b = *(const float4*)(muf + (size_t)grow * C2 + tq * 8 + 4);
        const float vv[8] = {a.x, a.y, a.z, a.w, b.x, b.y, b.z, b.w};
#pragma unroll
        for (int j = 0; j < 8; j++) {
          const unsigned short h = f2bf(vv[j]);
          hi[j] = (short)h;
          lo[j] = (short)f2bf(vv[j] - bf2f(h));
        }
      }
      *(short8*)(Hh + ((size_t)tq * 128 + r) * 8) = hi;
      if (!flag) *(short8*)(Hl + ((size_t)tq * 128 + r) * 8) = lo;
    }
  }
  __syncthreads();
  float4v acc[2][8];
#pragma unroll
  for (int mt = 0; mt < 2; mt++)
#pragma unroll
    for (int nt = 0; nt < 8; nt++) acc[mt][nt] = (float4v){0.f, 0.f, 0.f, 0.f};
#pragma unroll
  for (int kc2 = 0; kc2 < 2; kc2++) {
    const int kq = kc2 * 4 + quad;
    const int ra0 = w * 32 + r16;
    const int ra1 = w * 32 + 16 + r16;
    const short8 ah0 = *(const short8*)(Ah + ((size_t)kq * 128 + ra0) * 8);
    const short8 ah1 = *(const short8*)(Ah + ((size_t)kq * 128 + ra1) * 8);
    if (flag) {
#pragma unroll
      for (int nt = 0; nt < 8; nt++) {
        const short8 bh = *(const short8*)(Bh + ((size_t)kq * 128 + nt * 16 + r16) * 8);
        acc[0][nt] = mfma16(ah0, bh, acc[0][nt]);
        acc[1][nt] = mfma16(ah1, bh, acc[1][nt]);
      }
    } else {
      const short8 al0 = *(const short8*)(Al + ((size_t)kq * 128 + ra0) * 8);
      const short8 al1 = *(const short8*)(Al + ((size_t)kq * 128 + ra1) * 8);
#pragma unroll
      for (int nt = 0; nt < 8; nt++) {
        const short8 bh = *(const short8*)(Bh + ((size_t)kq * 128 + nt * 16 + r16) * 8);
        const short8 bl = *(const short8*)(Bl + ((size_t)kq * 128 + nt * 16 + r16) * 8);
        acc[0][nt] = mfma16(ah0, bh, acc[0][nt]);
        acc[0][nt] = mfma16(ah0, bl, acc[0][nt]);
        acc[0][nt] = mfma16(al0, bh, acc[0][nt]);
        acc[1][nt] = mfma16(ah1, bh, acc[1][nt]);
        acc[1][nt] = mfma16(ah1, bl, acc[1][nt]);
        acc[1][nt] = mfma16(al1, bh, acc[1][nt]);
      }
    }
  }
#pragma unroll
  for (int mt = 0; mt < 2; mt++) {
    const int row0 = rb + w * 32 + mt * 16 + quad * 4;
#pragma unroll
    for (int nt = 0; nt < 8; nt++) {
      const int col = cb + nt * 16 + r16;
#pragma unroll
      for (int r = 0; r < 4; r++) {
        if (flag) ((unsigned short*)outbase)[(size_t)(row0 + r) * N + col] = f2bf(acc[mt][nt][r]);
        else      ((float*)outbase)[(size_t)(row0 + r) * N + col] = acc[mt][nt][r];
      }
    }
  }
}

// fallback classpre (only used when no workspace)
__global__ __launch_bounds__(256) void k_classpre(const unsigned short* __restrict__ W1B,
                                                  const unsigned short* __restrict__ w1raw,
                                                  void* __restrict__ outbase) {
  const int flag = sniff_wave(w1raw);
  __shared__ float w1s[C2 * CP];
  for (int t = threadIdx.x; t < C2 * CP; t += 256) w1s[t] = bf2f(W1B[t]);
  __syncthreads();
  const float* muf = (const float*)((const char*)outbase + (size_t)N * N * 4);
  const unsigned short* mub = (const unsigned short*)((const char*)outbase + (size_t)N * N * 2);
  const int i = blockIdx.x * 256 + threadIdx.x;
  float logit[CP];
#pragma unroll
  for (int c = 0; c < CP; c++) logit[c] = 0.f;
  for (int k = 0; k < C2; k++) {
    const float m = flag ? bf2f(mub[(size_t)i * C2 + k]) : muf[(size_t)i * C2 + k];
#pragma unroll
    for (int c = 0; c < CP; c++) logit[c] += m * w1s[k * CP + c];
  }
  float mx = logit[0];
#pragma unroll
  for (int c = 1; c < CP; c++) mx = fmaxf(mx, logit[c]);
  float se = 0.f;
#pragma unroll
  for (int c = 0; c < CP; c++) { logit[c] = __expf(logit[c] - mx); se += logit[c]; }
  const float inv = 1.f / se;
  const size_t off = (size_t)N * N + (size_t)N * C2;
  if (flag) {
    unsigned short* o = (unsigned short*)outbase + off + (size_t)i * CP;
#pragma unroll
    for (int c = 0; c < CP; c++) o[c] = f2bf(logit[c] * inv);
  } else {
    float* o = (float*)outbase + off + (size_t)i * CP;
#pragma unroll
    for (int c = 0; c < CP; c++) o[c] = logit[c] * inv;
  }
}

// ---------------- launcher ----------------
// All scratch lives in d_out's recon region ([0, 128 MiB), valid for either
// out dtype; total ~126.7 MB < 134.2 MB). Recon launched LAST, reads nothing
// from that region.
extern "C" void kernel_launch(void* const* d_in, const int* in_sizes, int n_in,
                              void* d_out, int out_size, void* d_ws, size_t ws_size,
                              hipStream_t stream) {
  (void)in_sizes; (void)n_in; (void)out_size;
  const void* x   = d_in[0];                       // [N][F0]
  const int*  adj = (const int*)d_in[1];           // [N][N] i32
  const void* Whd = d_in[2];                       // [NH][F0][H1]
  const void* ah  = d_in[3];                       // [NH][2*H1]
  const void* Wo  = d_in[4];                       // [2*H1][C2]
  const void* ao  = d_in[5];                       // [2*C2]
  const unsigned short* W1 = (const unsigned short*)d_in[6];   // [C2][CP]

  char* ob = (char*)d_out;
  size_t off = 0;
  auto take = [&](size_t b) -> char* { char* p = ob + off; off += (b + 255) & ~(size_t)255; return p; };
  unsigned long long* MB = (unsigned long long*)take((size_t)N * N / 8);        //  8 MiB
  float*          PART1 = (float*)take((size_t)NS1 * NH * N * H1 * 4);          // 64 MiB
  float*          PART2 = (float*)take((size_t)NS2 * N * C2 * 4);               // 32 MiB
  unsigned short* Whp   = (unsigned short*)take((size_t)NH * N * H1 * 2);       //  4 MiB
  unsigned short* HBF   = (unsigned short*)take((size_t)N * 2 * H1 * 2);        //  4 MiB
  unsigned short* XB    = (unsigned short*)take((size_t)N * F0 * 2);            //  8 MiB
  unsigned short* Wh2P  = (unsigned short*)take((size_t)N * C2 * 2);            //  1 MiB
  unsigned short* WP1   = (unsigned short*)take((size_t)NH * F0 * H1 * 2);
  unsigned short* WP2   = (unsigned short*)take((size_t)2 * H1 * C2 * 2);
  unsigned short* ahB   = (unsigned short*)take((size_t)NH * 2 * H1 * 2);
  unsigned short* aoB   = (unsigned short*)take((size_t)2 * C2 * 2);
  unsigned short* W1B   = (unsigned short*)take((size_t)C2 * CP * 2);
  float*          F1    = (float*)take((size_t)NH * N * 4);
  float*          F2    = (float*)take((size_t)NH * N * 4);
  float*          F1B   = (float*)take((size_t)N * 4);
  float*          F2B   = (float*)take((size_t)N * 4);
  float*          DEN1P = (float*)take((size_t)NS1 * NH * N * 4);               // 512 KiB
  float*          DEN2P = (float*)take((size_t)NS2 * N * 4);                    // 512 KiB
  // total ~126.7 MB < 134.2 MB recon region (either out dtype)

  const bool fast = ws_size >= ((size_t)4 << 20);        // host-side size check only
  unsigned short* muP  = fast ? (unsigned short*)d_ws : nullptr;
  unsigned short* muPL = fast ? (unsigned short*)d_ws + (size_t)N * C2 : nullptr;

  const dim3 B(256);
  // fused setup: mask pack (big stream, first) + converts + weight pack backfill
  k_setup<<<dim3(MBB + CVB + PKB), B, 0, stream>>>(adj, MB, x, ah, ao, W1,
                                                   XB, ahB, aoB, W1B, Whd, Wo, WP1, WP2);

  k_gemm<F0, H1><<<dim3(N / 64, NH), B, 0, stream>>>(XB, WP1, Whp, ahB, F1, F2);
  k_attn<H1><<<dim3(N / 128, NH, NS1), B, 0, stream>>>((const unsigned char*)MB, F1, F2, Whp,
                                                       PART1, DEN1P, N / NS1);
  k_combine1<<<dim3((N * 2 * H1) / 256), B, 0, stream>>>(PART1, DEN1P, HBF);

  k_gemm<2 * H1, C2><<<dim3(N / 64, 1), B, 0, stream>>>(HBF, WP2, Wh2P, aoB, F1B, F2B);
  k_attn<C2><<<dim3(N / 128, 1, NS2), B, 0, stream>>>((const unsigned char*)MB, F1B, F2B, Wh2P,
                                                      PART2, DEN2P, N / NS2);
  k_combine2<<<dim3((N * C2) / 256), B, 0, stream>>>(PART2, DEN2P, W1B, W1, d_out, muP, muPL);

  if (fast) k_recon_fast<<<dim3(N / 128, N / 32), B, 0, stream>>>(muP, muPL, W1, d_out);
  else {
    k_classpre<<<dim3(N / 256), B, 0, stream>>>(W1B, W1, d_out);   // before recon!
    k_recon_lds<<<dim3(N / 128, N / 128), B, 0, stream>>>(W1, d_out);
  }
}